// Round 7
// baseline (194.363 us; speedup 1.0000x reference)
//
#include <hip/hip_runtime.h>
#include <hip/hip_bf16.h>
#include <cstdint>
#include <math.h>

// ---------------------------------------------------------------------------
// MyMultiHeadAttention: q/k/v proj (merged bf16 MFMA GEMM with FUSED f32->bf16
// A-staging, 2-phase dbuf, XCD panel swizzle, q pre-scaled by 1/8, coalesced
// vt epilogue) -> fused flash attention (paired causal q-tiles, 8 waves,
// swapped QK^T, in-register softmax+P, exact -1e9 semantics) -> output proj.
// B=8 S=1024 D=1024 H=16 Dh=64.
// ---------------------------------------------------------------------------

typedef __bf16 bf16_t;
typedef __bf16 bf16x8 __attribute__((ext_vector_type(8)));
typedef __bf16 bf16x4 __attribute__((ext_vector_type(4)));
typedef float  f32x4  __attribute__((ext_vector_type(4)));

#define MFMA16(a, b, c) __builtin_amdgcn_mfma_f32_16x16x32_bf16((a), (b), (c), 0, 0, 0)
#define NEGV (-1e9f)

__device__ __forceinline__ void gl_lds16(const void* gp, void* lp) {
  __builtin_amdgcn_global_load_lds(
      (__attribute__((address_space(1))) void*)(gp),
      (__attribute__((address_space(3))) void*)(lp), 16, 0, 0);
}

__device__ __forceinline__ unsigned int pk2(float lo, float hi) {
  unsigned short a = __builtin_bit_cast(unsigned short, (bf16_t)lo);
  unsigned short b = __builtin_bit_cast(unsigned short, (bf16_t)hi);
  return (unsigned int)a | ((unsigned int)b << 16);
}

// ---------------- f32 -> bf16 weight converts (8 elems/thread) --------------
__device__ __forceinline__ void cvt_body(const float* __restrict__ in,
                                         bf16_t* __restrict__ out, int i, int n8) {
  if (i < n8) {
    const float4* p = reinterpret_cast<const float4*>(in) + (size_t)i * 2;
    float4 a = p[0], b = p[1];
    bf16x8 r = {(bf16_t)a.x, (bf16_t)a.y, (bf16_t)a.z, (bf16_t)a.w,
                (bf16_t)b.x, (bf16_t)b.y, (bf16_t)b.z, (bf16_t)b.w};
    *reinterpret_cast<bf16x8*>(out + (size_t)i * 8) = r;
  }
}

__global__ __launch_bounds__(256) void cvt_w4(const float* __restrict__ a, const float* __restrict__ b,
                                              const float* __restrict__ c, const float* __restrict__ d,
                                              bf16_t* __restrict__ oa, bf16_t* __restrict__ ob,
                                              bf16_t* __restrict__ oc, bf16_t* __restrict__ od, int n8) {
  const float* in = blockIdx.y == 0 ? a : (blockIdx.y == 1 ? b : (blockIdx.y == 2 ? c : d));
  bf16_t* out     = blockIdx.y == 0 ? oa : (blockIdx.y == 1 ? ob : (blockIdx.y == 2 ? oc : od));
  cvt_body(in, out, blockIdx.x * 256 + threadIdx.x, n8);
}

// ---- XCD panel swizzle: 8 N-tiles of one M-panel land on one XCD ----------
__device__ __forceinline__ void panel_decode(int r, int& bx, int& by) {
  const int t8 = r >> 3;
  bx = t8 & 7;
  by = ((t8 >> 3) << 3) | (r & 7);
}

// ---------------- merged q/k/v projection GEMM (fused A-convert) ------------
// grid (512, 3): z=0 q-proj (bias, x0.125), z=1 k-proj, z=2 v-proj (vt via
// LDS-bounce coalesced epilogue).  A is f32 (converted during staging),
// W is pre-converted bf16.  C[m,n] = sum_k (bf16)A[m,k] * W[n,k].
__global__ __launch_bounds__(256) void gemm_qkv(const float* __restrict__ qf,
                                                const float* __restrict__ kf,
                                                const float* __restrict__ vf,
                                                const bf16_t* __restrict__ wqb,
                                                const bf16_t* __restrict__ wkb,
                                                const bf16_t* __restrict__ wvb,
                                                const float* __restrict__ bq,
                                                const float* __restrict__ bv,
                                                bf16_t* __restrict__ qp,
                                                bf16_t* __restrict__ kp,
                                                bf16_t* __restrict__ vtw) {
  __shared__ bf16_t smem[4][128 * 32];  // [0..1]=A dbuf, [2..3]=B dbuf (32 KiB)
  const int z = blockIdx.y;
  const float*  A = z == 0 ? qf : (z == 1 ? kf : vf);
  const bf16_t* W = z == 0 ? wqb : (z == 1 ? wkb : wvb);
  const int t = threadIdx.x;
  const int w = t >> 6, l = t & 63, lr = l & 15, lg = l >> 4;
  int bx, by;
  panel_decode((int)blockIdx.x, bx, by);
  const int m0 = by * 128, n0 = bx * 128;
  const int wm = (w >> 1) * 64, wn = (w & 1) * 64;
  const int K = 1024, N = 1024;

  f32x4 acc[4][4] = {};

  // A staging (f32 -> bf16 in regs): thread t covers row=t>>1, 16 f32 cols.
  const int arow = t >> 1, acol = (t & 1) * 16;
  const float* Agf = A + (size_t)(m0 + arow) * K + acol;
  char* adst0 = (char*)(smem[0]) + arow * 64 + (t & 1) * 32;
  char* adst1 = (char*)(smem[1]) + arow * 64 + (t & 1) * 32;
  // B staging (bf16 weights via global_load_lds)
  const bf16_t* Wg = W + (size_t)(n0 + (t >> 2)) * K + (t & 3) * 8;

  float4 a0, a1, a2, a3;
  auto loadA = [&](int kt) {
    const float4* p = reinterpret_cast<const float4*>(Agf + kt);
    a0 = p[0]; a1 = p[1]; a2 = p[2]; a3 = p[3];
  };
  auto writeA = [&](int buf) {
    bf16x8 r0 = {(bf16_t)a0.x, (bf16_t)a0.y, (bf16_t)a0.z, (bf16_t)a0.w,
                 (bf16_t)a1.x, (bf16_t)a1.y, (bf16_t)a1.z, (bf16_t)a1.w};
    bf16x8 r1 = {(bf16_t)a2.x, (bf16_t)a2.y, (bf16_t)a2.z, (bf16_t)a2.w,
                 (bf16_t)a3.x, (bf16_t)a3.y, (bf16_t)a3.z, (bf16_t)a3.w};
    char* d = buf ? adst1 : adst0;
    *reinterpret_cast<bf16x8*>(d) = r0;
    *reinterpret_cast<bf16x8*>(d + 16) = r1;
  };
  auto stageB = [&](int buf, int kt) {
    gl_lds16(Wg + kt,                  (char*)(smem[2 + buf]) + t * 16);
    gl_lds16(Wg + kt + (size_t)64 * K, (char*)(smem[2 + buf]) + 4096 + t * 16);
  };

  // prologue
  loadA(0);
  stageB(0, 0);
  writeA(0);
  __syncthreads();  // implicit vmcnt(0)+lgkmcnt(0): buf0 ready

  for (int it = 0; it < 32; ++it) {
    const int cur = it & 1;
    if (it < 31) {
      loadA((it + 1) * 32);       // f32 A loads: latency hides under MFMA
      stageB(cur ^ 1, (it + 1) * 32);
    }
    const char* AsB = (const char*)(smem[cur]);
    const char* BsB = (const char*)(smem[2 + cur]);
    bf16x8 af[4], bfr[4];
#pragma unroll
    for (int mt = 0; mt < 4; mt++)
      af[mt] = *reinterpret_cast<const bf16x8*>(AsB + ((wm + mt * 16 + lr) * 32 + lg * 8) * 2);
#pragma unroll
    for (int nt = 0; nt < 4; nt++)
      bfr[nt] = *reinterpret_cast<const bf16x8*>(BsB + ((wn + nt * 16 + lr) * 32 + lg * 8) * 2);
#pragma unroll
    for (int mt = 0; mt < 4; mt++)
#pragma unroll
      for (int nt = 0; nt < 4; nt++)
        acc[mt][nt] = MFMA16(af[mt], bfr[nt], acc[mt][nt]);
    if (it < 31) writeA(cur ^ 1);   // cvt + ds_write after MFMA issue
    __syncthreads();  // drains: B gl_lds (vmcnt), A ds_writes + reads (lgkm)
  }

  if (z != 2) {
    bf16_t* outp = (z == 0) ? qp : kp;
    const float sc = (z == 0) ? 0.125f : 1.0f;  // fold attention's /8 (exact)
#pragma unroll
    for (int nt = 0; nt < 4; nt++) {
      const int col = n0 + wn + nt * 16 + lr;
      const float bb = (z == 0) ? bq[col] : 0.0f;
#pragma unroll
      for (int mt = 0; mt < 4; mt++)
#pragma unroll
        for (int i = 0; i < 4; i++) {
          const int row = m0 + wm + mt * 16 + lg * 4 + i;
          outp[(size_t)row * N + col] = (bf16_t)((acc[mt][nt][i] + bb) * sc);
        }
    }
  } else {
    // vt epilogue: C^T -> LDS (16B-chunk XOR swizzle) -> coalesced 128B rows.
    char* T = (char*)smem;  // 32 KiB, K-loop done
#pragma unroll
    for (int nt = 0; nt < 4; nt++) {
      const int col_l = wn + nt * 16 + lr;
      const float bb = bv[n0 + col_l];
#pragma unroll
      for (int mt = 0; mt < 4; mt++)
#pragma unroll
        for (int i = 0; i < 4; i++) {
          const int row_l = wm + mt * 16 + lg * 4 + i;
          *(bf16_t*)(T + col_l * 256 + ((row_l * 2) ^ ((col_l & 7) << 4))) =
              (bf16_t)(acc[mt][nt][i] + bb);
        }
    }
    __syncthreads();
    const int b = m0 >> 10, s0 = m0 & 1023;
    const int c_l = t >> 1, half = t & 1;
    bf16_t* dst = vtw + (size_t)(b * 1024 + n0 + c_l) * 1024 + s0 + half * 64;
    const char* Trow = T + c_l * 256;
    const int sw = c_l & 7;
#pragma unroll
    for (int jj = 0; jj < 8; jj++) {
      const int lc = half * 8 + jj;
      bf16x8 vv = *reinterpret_cast<const bf16x8*>(Trow + ((lc ^ sw) << 4));
      *reinterpret_cast<bf16x8*>(dst + jj * 8) = vv;
    }
  }
}

// ---------------- final GEMM: f32 out, bias, 2-phase dbuf ----------------
__global__ __launch_bounds__(256) void gemm_out(const bf16_t* __restrict__ A,
                                                const bf16_t* __restrict__ W,
                                                const float* __restrict__ bias,
                                                float* __restrict__ outp) {
  __shared__ bf16_t smem[4][128 * 32];
  const int t = threadIdx.x;
  const int w = t >> 6, l = t & 63, lr = l & 15, lg = l >> 4;
  int bx, by;
  panel_decode((int)blockIdx.x, bx, by);
  const int m0 = by * 128, n0 = bx * 128;
  const int wm = (w >> 1) * 64, wn = (w & 1) * 64;
  const int K = 1024, N = 1024;

  f32x4 acc[4][4] = {};
  const bf16_t* Ag = A + (size_t)(m0 + (t >> 2)) * K + (t & 3) * 8;
  const bf16_t* Wg = W + (size_t)(n0 + (t >> 2)) * K + (t & 3) * 8;

  auto stage = [&](int buf, int kt) {
    gl_lds16(Ag + kt,                  (char*)(smem[buf])     + t * 16);
    gl_lds16(Ag + kt + (size_t)64 * K, (char*)(smem[buf])     + 4096 + t * 16);
    gl_lds16(Wg + kt,                  (char*)(smem[2 + buf]) + t * 16);
    gl_lds16(Wg + kt + (size_t)64 * K, (char*)(smem[2 + buf]) + 4096 + t * 16);
  };

  stage(0, 0);
  __syncthreads();

  for (int it = 0; it < 32; ++it) {
    const int cur = it & 1;
    if (it < 31) stage(cur ^ 1, (it + 1) * 32);

    const char* AsB = (const char*)(smem[cur]);
    const char* BsB = (const char*)(smem[2 + cur]);
    bf16x8 af[4], bfr[4];
#pragma unroll
    for (int mt = 0; mt < 4; mt++)
      af[mt] = *reinterpret_cast<const bf16x8*>(AsB + ((wm + mt * 16 + lr) * 32 + lg * 8) * 2);
#pragma unroll
    for (int nt = 0; nt < 4; nt++)
      bfr[nt] = *reinterpret_cast<const bf16x8*>(BsB + ((wn + nt * 16 + lr) * 32 + lg * 8) * 2);
#pragma unroll
    for (int mt = 0; mt < 4; mt++)
#pragma unroll
      for (int nt = 0; nt < 4; nt++)
        acc[mt][nt] = MFMA16(af[mt], bfr[nt], acc[mt][nt]);
    __syncthreads();
  }

#pragma unroll
  for (int nt = 0; nt < 4; nt++) {
    const int col = n0 + wn + nt * 16 + lr;
    const float bb = bias[col];
#pragma unroll
    for (int mt = 0; mt < 4; mt++)
#pragma unroll
      for (int i = 0; i < 4; i++) {
        const int row = m0 + wm + mt * 16 + lg * 4 + i;
        outp[(size_t)row * N + col] = acc[mt][nt][i] + bb;
      }
  }
}

// ---------------- in-register P pack + butterfly (16-lane groups) ----------
__device__ __forceinline__ void pack_bfly(const f32x4 (&s)[4], int lg,
                                          bf16x8& pbv0, bf16x8& pbv1) {
  unsigned int u[4][2], sh[4][2];
#pragma unroll
  for (int nt = 0; nt < 4; nt++) {
    u[nt][0] = pk2(s[nt][0], s[nt][1]);
    u[nt][1] = pk2(s[nt][2], s[nt][3]);
  }
#pragma unroll
  for (int nt = 0; nt < 4; nt++) {
    sh[nt][0] = (unsigned int)__shfl_xor((int)u[nt][0], 16, 64);
    sh[nt][1] = (unsigned int)__shfl_xor((int)u[nt][1], 16, 64);
  }
  const bool ev = (lg & 1) == 0;
  unsigned int Y[8];
  Y[0] = ev ? u[0][0] : sh[1][0];  Y[1] = ev ? u[0][1] : sh[1][1];
  Y[2] = ev ? u[2][0] : sh[3][0];  Y[3] = ev ? u[2][1] : sh[3][1];
  Y[4] = ev ? sh[0][0] : u[1][0];  Y[5] = ev ? sh[0][1] : u[1][1];
  Y[6] = ev ? sh[2][0] : u[3][0];  Y[7] = ev ? sh[2][1] : u[3][1];
  const bool mid = (lg == 1) || (lg == 2);
#pragma unroll
  for (int j = 0; j < 8; j++) {
    const unsigned int z = (unsigned int)__shfl_xor((int)Y[j], 48, 64);
    Y[j] = mid ? z : Y[j];
  }
  union U8 { unsigned int u[4]; bf16x8 v; };
  U8 p0, p1;
  p0.u[0] = Y[0]; p0.u[1] = Y[1]; p0.u[2] = Y[4]; p0.u[3] = Y[5];
  p1.u[0] = Y[2]; p1.u[1] = Y[3]; p1.u[2] = Y[6]; p1.u[3] = Y[7];
  pbv0 = p0.v;
  pbv1 = p1.v;
}

// ---------------- fused flash attention (paired q-tiles, 8 waves) ----------
// Grid 1024: bh = (L&7)+8*(L>>6) (16 bh/XCD), j = (L>>3)&7.
// Block handles q-tiles lo=j (waves 4-7) and hi=15-j (waves 0-3), sharing one
// K/V staging stream over k-tiles 0..hi.  qp pre-scaled by 0.125 (exact).
__global__ __launch_bounds__(512, 8) void attn_fused(const bf16_t* __restrict__ qp,
                                                     const bf16_t* __restrict__ kp,
                                                     const bf16_t* __restrict__ vt,
                                                     const int* __restrict__ pad,
                                                     bf16_t* __restrict__ outp) {
  __shared__ bf16_t Ks[2][64 * 64];   // [key][dh], XOR-swizzled
  __shared__ bf16_t Vts[2][64 * 64];  // [dh][key], XOR-swizzled
  __shared__ int padI[1024];
  __shared__ int sfl[8], sfh[8];
  const int t = threadIdx.x, w = t >> 6, l = t & 63, lr = l & 15, lg = l >> 4;
  const int L = (int)blockIdx.x;
  const int bh = (L & 7) + ((L >> 6) << 3);
  const int j = (L >> 3) & 7;
  const int b = bh >> 4, h = bh & 15;
  const int lo = j, hi = 15 - j;

  const int srow = t >> 3, sc = t & 7;
  const int gc = sc ^ (srow & 7);  // pre-swizzled global chunk
  const bf16_t* kgb = kp + (size_t)(b * 1024 + srow) * 1024 + h * 64 + gc * 8;
  const bf16_t* vgb = vt + (size_t)(bh * 64 + srow) * 1024 + gc * 8;

  auto stage = [&](int bufi, int k0s) {
    gl_lds16(kgb + (size_t)k0s * 1024, (char*)(Ks[bufi]) + t * 16);
    gl_lds16(vgb + k0s,                (char*)(Vts[bufi]) + t * 16);
  };

  // degenerate-row checks: any unpadded key in [0, lo*64] / [0, hi*64]?
  bool unl = false, unh = false;
  for (int jj = t; jj <= hi * 64; jj += 512) {
    const bool u = (pad[b * 1024 + jj] == 0);
    unh |= u;
    unl |= (u && (jj <= lo * 64));
  }
  const bool al = __any(unl), ah = __any(unh);
  if (l == 0) { sfl[w] = al ? 1 : 0; sfh[w] = ah ? 1 : 0; }

  stage(0, 0);
  if (t < 256) gl_lds16(pad + b * 1024 + t * 4, (char*)padI + t * 16);

  // this wave's q-tile: waves 0-3 -> hi, waves 4-7 -> lo
  const int mytile = (w < 4) ? hi : lo;
  const int qrow_l = mytile * 64 + (w & 3) * 16 + lr;  // lane's q row
  const int base16 = mytile * 64 + (w & 3) * 16;
  const bf16_t* qg = qp + (size_t)(b * 1024 + qrow_l) * 1024 + h * 64 + lg * 8;
  const bf16x8 qa0 = *reinterpret_cast<const bf16x8*>(qg);
  const bf16x8 qa1 = *reinterpret_cast<const bf16x8*>(qg + 32);

  __syncthreads();  // sf ready; drains tile-0 staging + padI
  int ul = 0, uh = 0;
#pragma unroll
  for (int i = 0; i < 8; i++) { ul |= sfl[i]; uh |= sfh[i]; }
  const bool mydeg = (w < 4) ? (uh == 0) : (ul == 0);
  const int ktEnd = (ul == 0) ? 16 : (hi + 1);

  f32x4 o[4] = {};
  float m_ = -INFINITY, ld_ = 0.0f;

  for (int kt = 0; kt < ktEnd; ++kt) {
    const int cur = kt & 1;
    if (kt + 1 < ktEnd) {
      stage(cur ^ 1, (kt + 1) * 64);
      asm volatile("s_waitcnt vmcnt(2)" ::: "memory");
    } else {
      asm volatile("s_waitcnt vmcnt(0)" ::: "memory");
    }
    __builtin_amdgcn_s_barrier();

    if (kt <= mytile || mydeg) {
      const char* Kb = (const char*)(Ks[cur]);
      const char* Vb = (const char*)(Vts[cur]);
      const int k0 = kt * 64;

      // S^T = K * Q^T : s[nt][i] = score[key=k0+nt*16+lg*4+i][q=qrow_l]
      f32x4 s[4] = {};
#pragma unroll
      for (int nt = 0; nt < 4; nt++) {
        const int row = nt * 16 + lr;
        const int sw = (row & 7) << 4;
        bf16x8 kb0 = *reinterpret_cast<const bf16x8*>(Kb + row * 128 + ((lg * 16) ^ sw));
        bf16x8 kb1 = *reinterpret_cast<const bf16x8*>(Kb + row * 128 + ((lg * 16 + 64) ^ sw));
        s[nt] = MFMA16(kb0, qa0, s[nt]);
        s[nt] = MFMA16(kb1, qa1, s[nt]);
      }

      // masking — reference f32 arithmetic exactly (qp pre-scaled by 1/8)
      const bool nc = (k0 + 63 > base16);
#pragma unroll
      for (int nt = 0; nt < 4; nt++) {
        const int kc4 = k0 + nt * 16 + lg * 4;
        const int4 pd = *reinterpret_cast<const int4*>(&padI[kc4]);
        const int pdv[4] = {pd.x, pd.y, pd.z, pd.w};
#pragma unroll
        for (int i = 0; i < 4; i++) {
          float v = s[nt][i];
          if (pdv[i]) v = NEGV;
          if (nc && (kc4 + i > qrow_l)) v += NEGV;
          s[nt][i] = v;
        }
      }

      // row max: 15 reg-local fmax + 2 shfl
      float mx = s[0][0];
#pragma unroll
      for (int nt = 0; nt < 4; nt++)
#pragma unroll
        for (int i = 0; i < 4; i++) mx = fmaxf(mx, s[nt][i]);
      mx = fmaxf(mx, __shfl_xor(mx, 16, 64));
      mx = fmaxf(mx, __shfl_xor(mx, 32, 64));

      if (!__all(mx <= m_ - 88.0f)) {          // dynamic underflow skip
        if (!__all(mx <= m_ + 8.0f)) {         // defer-max rescale
          const float mn = fmaxf(m_, mx);
          const float scl = __expf(m_ - mn);
          m_ = mn;
          ld_ *= scl;
#pragma unroll
          for (int nt = 0; nt < 4; nt++) o[nt] *= scl;
        }
        float a = 0.0f;
#pragma unroll
        for (int nt = 0; nt < 4; nt++)
#pragma unroll
          for (int i = 0; i < 4; i++) {
            const float p = __expf(s[nt][i] - m_);
            s[nt][i] = p;
            a += p;
          }
        a += __shfl_xor(a, 16, 64);
        a += __shfl_xor(a, 32, 64);
        ld_ += a;

        bf16x8 pb0, pb1;
        pack_bfly(s, lg, pb0, pb1);

        // PV: O^T[d][q] += V^T[d][k] * P^T[k][q]
#pragma unroll
        for (int nt = 0; nt < 4; nt++) {
          const int vrow = nt * 16 + lr;
          const int vsw = (vrow & 7) << 4;
          bf16x8 vf0 = *reinterpret_cast<const bf16x8*>(Vb + vrow * 128 + ((lg * 16) ^ vsw));
          bf16x8 vf1 = *reinterpret_cast<const bf16x8*>(Vb + vrow * 128 + ((64 + lg * 16) ^ vsw));
          o[nt] = MFMA16(vf0, pb0, o[nt]);
          o[nt] = MFMA16(vf1, pb1, o[nt]);
        }
      }
    }
    __builtin_amdgcn_s_barrier();  // protect buf[cur] before next prefetch
  }

  // epilogue: o^T[d = nt*16+lg*4+i][q = lr], normalize, 8B vector stores
  const float rinv = 1.0f / ld_;
#pragma unroll
  for (int nt = 0; nt < 4; nt++) {
    bf16x4 r = {(bf16_t)(o[nt][0] * rinv), (bf16_t)(o[nt][1] * rinv),
                (bf16_t)(o[nt][2] * rinv), (bf16_t)(o[nt][3] * rinv)};
    *reinterpret_cast<bf16x4*>(outp + (size_t)(b * 1024 + qrow_l) * 1024 + h * 64 + nt * 16 + lg * 4) = r;
  }
}

// ---------------------------------------------------------------------------
extern "C" void kernel_launch(void* const* d_in, const int* in_sizes, int n_in,
                              void* d_out, int out_size, void* d_ws, size_t ws_size,
                              hipStream_t stream) {
  const float* q   = (const float*)d_in[0];
  const float* k   = (const float*)d_in[1];
  const float* v   = (const float*)d_in[2];
  const int*   pad = (const int*)d_in[3];
  const float* wq  = (const float*)d_in[5];
  const float* bq  = (const float*)d_in[6];
  const float* wk  = (const float*)d_in[7];
  const float* wv  = (const float*)d_in[8];
  const float* bv  = (const float*)d_in[9];
  const float* wo  = (const float*)d_in[10];
  const float* bo  = (const float*)d_in[11];

  const int nW = 1024 * 1024;

  char* ws = (char*)d_ws;
  const size_t MiB = 1024 * 1024;
  bf16_t* attnO = (bf16_t*)(ws + 0 * MiB);   // 16 MiB
  bf16_t* qp  = (bf16_t*)(ws + 48 * MiB);
  bf16_t* kp  = (bf16_t*)(ws + 64 * MiB);
  bf16_t* vtw = (bf16_t*)(ws + 80 * MiB);
  bf16_t* wqb = (bf16_t*)(ws + 96 * MiB);
  bf16_t* wkb = (bf16_t*)(ws + 98 * MiB);
  bf16_t* wvb = (bf16_t*)(ws + 100 * MiB);
  bf16_t* wob = (bf16_t*)(ws + 102 * MiB);

  cvt_w4<<<dim3(nW / 2048, 4), 256, 0, stream>>>(wq, wk, wv, wo, wqb, wkb, wvb, wob, nW / 8);

  gemm_qkv<<<dim3(512, 3), 256, 0, stream>>>(q, k, v, wqb, wkb, wvb, bq, bv, qp, kp, vtw);

  attn_fused<<<1024, 512, 0, stream>>>(qp, kp, vtw, pad, attnO);

  gemm_out<<<512, 256, 0, stream>>>(attnO, wob, bo, (float*)d_out);
}

// Round 8
// 187.378 us; speedup vs baseline: 1.0373x; 1.0373x over previous
//
#include <hip/hip_runtime.h>
#include <hip/hip_bf16.h>
#include <cstdint>
#include <math.h>

// ---------------------------------------------------------------------------
// MyMultiHeadAttention: cvt (1 launch) -> q/k/v proj (merged bf16 MFMA GEMM,
// depth-2 counted-vmcnt pipeline, T2 chunk swizzle, XCD panel swizzle,
// q pre-scaled 1/8, coalesced vt epilogue) -> fused flash attention (paired
// causal q-tiles, 8 waves, swapped QK^T, in-register softmax+P, exact -1e9
// semantics) -> output proj (same pipelined GEMM, f32 out).
// B=8 S=1024 D=1024 H=16 Dh=64.
// ---------------------------------------------------------------------------

typedef __bf16 bf16_t;
typedef __bf16 bf16x8 __attribute__((ext_vector_type(8)));
typedef __bf16 bf16x4 __attribute__((ext_vector_type(4)));
typedef float  f32x4  __attribute__((ext_vector_type(4)));

#define MFMA16(a, b, c) __builtin_amdgcn_mfma_f32_16x16x32_bf16((a), (b), (c), 0, 0, 0)
#define NEGV (-1e9f)

__device__ __forceinline__ void gl_lds16(const void* gp, void* lp) {
  __builtin_amdgcn_global_load_lds(
      (__attribute__((address_space(1))) void*)(gp),
      (__attribute__((address_space(3))) void*)(lp), 16, 0, 0);
}

__device__ __forceinline__ unsigned int pk2(float lo, float hi) {
  unsigned short a = __builtin_bit_cast(unsigned short, (bf16_t)lo);
  unsigned short b = __builtin_bit_cast(unsigned short, (bf16_t)hi);
  return (unsigned int)a | ((unsigned int)b << 16);
}

// ---------------- f32 -> bf16 bulk convert, single launch -------------------
__device__ __forceinline__ void cvt_body(const float* __restrict__ in,
                                         bf16_t* __restrict__ out, int i) {
  const float4* p = reinterpret_cast<const float4*>(in) + (size_t)i * 2;
  float4 a = p[0], b = p[1];
  bf16x8 r = {(bf16_t)a.x, (bf16_t)a.y, (bf16_t)a.z, (bf16_t)a.w,
              (bf16_t)b.x, (bf16_t)b.y, (bf16_t)b.z, (bf16_t)b.w};
  *reinterpret_cast<bf16x8*>(out + (size_t)i * 8) = r;
}

// blocks 0..12287: q/k/v (4096 each, exact).  12288..14335: 4 weights (512 each).
__global__ __launch_bounds__(256) void cvt_all(
    const float* __restrict__ q, const float* __restrict__ k, const float* __restrict__ v,
    const float* __restrict__ wq, const float* __restrict__ wk,
    const float* __restrict__ wv, const float* __restrict__ wo,
    bf16_t* __restrict__ oq, bf16_t* __restrict__ ok, bf16_t* __restrict__ ov,
    bf16_t* __restrict__ owq, bf16_t* __restrict__ owk,
    bf16_t* __restrict__ owv, bf16_t* __restrict__ owo) {
  const int bid = (int)blockIdx.x;
  if (bid < 12288) {
    const int s = bid >> 12;
    const int i = (bid & 4095) * 256 + (int)threadIdx.x;
    cvt_body(s == 0 ? q : (s == 1 ? k : v),
             s == 0 ? oq : (s == 1 ? ok : ov), i);
  } else {
    const int r = bid - 12288;
    const int s = r >> 9;
    const int i = (r & 511) * 256 + (int)threadIdx.x;
    cvt_body(s == 0 ? wq : (s == 1 ? wk : (s == 2 ? wv : wo)),
             s == 0 ? owq : (s == 1 ? owk : (s == 2 ? owv : owo)), i);
  }
}

// ---- XCD panel swizzle: 8 N-tiles of one M-panel land on one XCD ----------
__device__ __forceinline__ void panel_decode(int r, int& bx, int& by) {
  const int t8 = r >> 3;
  bx = t8 & 7;
  by = ((t8 >> 3) << 3) | (r & 7);
}

// ---------------- merged q/k/v projection GEMM ------------------------------
// Depth-2 pipeline: 3 buf pairs, vmcnt(4) counted wait (tile i retired; i+1,
// i+2 stay in flight across the barrier), 1 barrier/iter, never drain to 0.
// LDS chunk swizzle: LDS[r][c] holds global 16B-chunk c ^ ((r>>1)&3); source
// pre-swizzled (gl_lds dest is linear), reads XOR the same -> 8-way conflict
// becomes 2-way (free).
// grid (512, 3): z=0 q-proj (bias, x0.125), z=1 k-proj, z=2 v-proj (vt).
__global__ __launch_bounds__(256) void gemm_qkv(const bf16_t* __restrict__ qbf,
                                                const bf16_t* __restrict__ kbf,
                                                const bf16_t* __restrict__ vbf,
                                                const bf16_t* __restrict__ wqb,
                                                const bf16_t* __restrict__ wkb,
                                                const bf16_t* __restrict__ wvb,
                                                const float* __restrict__ bq,
                                                const float* __restrict__ bv,
                                                bf16_t* __restrict__ qp,
                                                bf16_t* __restrict__ kp,
                                                bf16_t* __restrict__ vtw) {
  __shared__ bf16_t smem[6][128 * 32];  // A bufs 0..2, B bufs 3..5 (48 KiB)
  const int z = blockIdx.y;
  const bf16_t* A = z == 0 ? qbf : (z == 1 ? kbf : vbf);
  const bf16_t* W = z == 0 ? wqb : (z == 1 ? wkb : wvb);
  const int t = threadIdx.x;
  const int w = t >> 6, l = t & 63, lr = l & 15, lg = l >> 4;
  int bx, by;
  panel_decode((int)blockIdx.x, bx, by);
  const int m0 = by * 128, n0 = bx * 128;
  const int wm = (w >> 1) * 64, wn = (w & 1) * 64;
  const int K = 1024, N = 1024;

  f32x4 acc[4][4] = {};
  // staging source: row t>>2 (and +64), chunk (t&3) ^ swizzle(row); row>>1&3
  // == (t>>3)&3 for both row halves (64 is swizzle-neutral).
  const int swsrc = ((t & 3) ^ ((t >> 3) & 3)) * 8;
  const bf16_t* Ag = A + (size_t)(m0 + (t >> 2)) * K + swsrc;
  const bf16_t* Wg = W + (size_t)(n0 + (t >> 2)) * K + swsrc;

  auto stage = [&](int buf, int tile) {
    const int kt = tile * 32;
    gl_lds16(Ag + kt,                  (char*)(smem[buf])     + t * 16);
    gl_lds16(Ag + kt + (size_t)64 * K, (char*)(smem[buf])     + 4096 + t * 16);
    gl_lds16(Wg + kt,                  (char*)(smem[3 + buf]) + t * 16);
    gl_lds16(Wg + kt + (size_t)64 * K, (char*)(smem[3 + buf]) + 4096 + t * 16);
  };

  stage(0, 0);
  stage(1, 1);  // 8 outstanding/wave

  const int cofs = ((lg ^ ((lr >> 1) & 3)) << 4);  // read swizzle (row>>1&3 == lr>>1&3)
  for (int it = 0; it < 32; ++it) {
    if (it < 31) asm volatile("s_waitcnt vmcnt(4)" ::: "memory");  // tile it landed
    else         asm volatile("s_waitcnt vmcnt(0)" ::: "memory");
    __builtin_amdgcn_s_barrier();  // tile it visible; buf (it+2)%3 readers done
    if (it + 2 < 32) stage((it + 2) % 3, it + 2);

    const char* AsB = (const char*)(smem[it % 3]);
    const char* BsB = (const char*)(smem[3 + it % 3]);
    bf16x8 af[4], bfr[4];
#pragma unroll
    for (int mt = 0; mt < 4; mt++)
      af[mt] = *reinterpret_cast<const bf16x8*>(AsB + (wm + mt * 16 + lr) * 64 + cofs);
#pragma unroll
    for (int nt = 0; nt < 4; nt++)
      bfr[nt] = *reinterpret_cast<const bf16x8*>(BsB + (wn + nt * 16 + lr) * 64 + cofs);
#pragma unroll
    for (int mt = 0; mt < 4; mt++)
#pragma unroll
      for (int nt = 0; nt < 4; nt++)
        acc[mt][nt] = MFMA16(af[mt], bfr[nt], acc[mt][nt]);
    // no trailing barrier: next iter's vmcnt+barrier covers all hazards
  }

  if (z != 2) {
    bf16_t* outp = (z == 0) ? qp : kp;
    const float sc = (z == 0) ? 0.125f : 1.0f;  // fold attention's /8 (exact)
#pragma unroll
    for (int nt = 0; nt < 4; nt++) {
      const int col = n0 + wn + nt * 16 + lr;
      const float bb = (z == 0) ? bq[col] : 0.0f;
#pragma unroll
      for (int mt = 0; mt < 4; mt++)
#pragma unroll
        for (int i = 0; i < 4; i++) {
          const int row = m0 + wm + mt * 16 + lg * 4 + i;
          outp[(size_t)row * N + col] = (bf16_t)((acc[mt][nt][i] + bb) * sc);
        }
    }
  } else {
    // vt epilogue: C^T -> LDS (16B-chunk XOR swizzle) -> coalesced 128B rows.
    __syncthreads();  // all waves done reading K-loop buffers before reuse
    char* T = (char*)smem;  // 32 KiB of the 48 KiB block
#pragma unroll
    for (int nt = 0; nt < 4; nt++) {
      const int col_l = wn + nt * 16 + lr;
      const float bb = bv[n0 + col_l];
#pragma unroll
      for (int mt = 0; mt < 4; mt++)
#pragma unroll
        for (int i = 0; i < 4; i++) {
          const int row_l = wm + mt * 16 + lg * 4 + i;
          *(bf16_t*)(T + col_l * 256 + ((row_l * 2) ^ ((col_l & 7) << 4))) =
              (bf16_t)(acc[mt][nt][i] + bb);
        }
    }
    __syncthreads();
    const int b = m0 >> 10, s0 = m0 & 1023;
    const int c_l = t >> 1, half = t & 1;
    bf16_t* dst = vtw + (size_t)(b * 1024 + n0 + c_l) * 1024 + s0 + half * 64;
    const char* Trow = T + c_l * 256;
    const int sw = c_l & 7;
#pragma unroll
    for (int jj = 0; jj < 8; jj++) {
      const int lc = half * 8 + jj;
      bf16x8 vv = *reinterpret_cast<const bf16x8*>(Trow + ((lc ^ sw) << 4));
      *reinterpret_cast<bf16x8*>(dst + jj * 8) = vv;
    }
  }
}

// ---------------- final GEMM: f32 out, bias, same pipeline ----------------
__global__ __launch_bounds__(256) void gemm_out(const bf16_t* __restrict__ A,
                                                const bf16_t* __restrict__ W,
                                                const float* __restrict__ bias,
                                                float* __restrict__ outp) {
  __shared__ bf16_t smem[6][128 * 32];
  const int t = threadIdx.x;
  const int w = t >> 6, l = t & 63, lr = l & 15, lg = l >> 4;
  int bx, by;
  panel_decode((int)blockIdx.x, bx, by);
  const int m0 = by * 128, n0 = bx * 128;
  const int wm = (w >> 1) * 64, wn = (w & 1) * 64;
  const int K = 1024, N = 1024;

  f32x4 acc[4][4] = {};
  const int swsrc = ((t & 3) ^ ((t >> 3) & 3)) * 8;
  const bf16_t* Ag = A + (size_t)(m0 + (t >> 2)) * K + swsrc;
  const bf16_t* Wg = W + (size_t)(n0 + (t >> 2)) * K + swsrc;

  auto stage = [&](int buf, int tile) {
    const int kt = tile * 32;
    gl_lds16(Ag + kt,                  (char*)(smem[buf])     + t * 16);
    gl_lds16(Ag + kt + (size_t)64 * K, (char*)(smem[buf])     + 4096 + t * 16);
    gl_lds16(Wg + kt,                  (char*)(smem[3 + buf]) + t * 16);
    gl_lds16(Wg + kt + (size_t)64 * K, (char*)(smem[3 + buf]) + 4096 + t * 16);
  };

  stage(0, 0);
  stage(1, 1);

  const int cofs = ((lg ^ ((lr >> 1) & 3)) << 4);
  for (int it = 0; it < 32; ++it) {
    if (it < 31) asm volatile("s_waitcnt vmcnt(4)" ::: "memory");
    else         asm volatile("s_waitcnt vmcnt(0)" ::: "memory");
    __builtin_amdgcn_s_barrier();
    if (it + 2 < 32) stage((it + 2) % 3, it + 2);

    const char* AsB = (const char*)(smem[it % 3]);
    const char* BsB = (const char*)(smem[3 + it % 3]);
    bf16x8 af[4], bfr[4];
#pragma unroll
    for (int mt = 0; mt < 4; mt++)
      af[mt] = *reinterpret_cast<const bf16x8*>(AsB + (wm + mt * 16 + lr) * 64 + cofs);
#pragma unroll
    for (int nt = 0; nt < 4; nt++)
      bfr[nt] = *reinterpret_cast<const bf16x8*>(BsB + (wn + nt * 16 + lr) * 64 + cofs);
#pragma unroll
    for (int mt = 0; mt < 4; mt++)
#pragma unroll
      for (int nt = 0; nt < 4; nt++)
        acc[mt][nt] = MFMA16(af[mt], bfr[nt], acc[mt][nt]);
  }

#pragma unroll
  for (int nt = 0; nt < 4; nt++) {
    const int col = n0 + wn + nt * 16 + lr;
    const float bb = bias[col];
#pragma unroll
    for (int mt = 0; mt < 4; mt++)
#pragma unroll
      for (int i = 0; i < 4; i++) {
        const int row = m0 + wm + mt * 16 + lg * 4 + i;
        outp[(size_t)row * N + col] = acc[mt][nt][i] + bb;
      }
  }
}

// ---------------- in-register P pack + butterfly (16-lane groups) ----------
__device__ __forceinline__ void pack_bfly(const f32x4 (&s)[4], int lg,
                                          bf16x8& pbv0, bf16x8& pbv1) {
  unsigned int u[4][2], sh[4][2];
#pragma unroll
  for (int nt = 0; nt < 4; nt++) {
    u[nt][0] = pk2(s[nt][0], s[nt][1]);
    u[nt][1] = pk2(s[nt][2], s[nt][3]);
  }
#pragma unroll
  for (int nt = 0; nt < 4; nt++) {
    sh[nt][0] = (unsigned int)__shfl_xor((int)u[nt][0], 16, 64);
    sh[nt][1] = (unsigned int)__shfl_xor((int)u[nt][1], 16, 64);
  }
  const bool ev = (lg & 1) == 0;
  unsigned int Y[8];
  Y[0] = ev ? u[0][0] : sh[1][0];  Y[1] = ev ? u[0][1] : sh[1][1];
  Y[2] = ev ? u[2][0] : sh[3][0];  Y[3] = ev ? u[2][1] : sh[3][1];
  Y[4] = ev ? sh[0][0] : u[1][0];  Y[5] = ev ? sh[0][1] : u[1][1];
  Y[6] = ev ? sh[2][0] : u[3][0];  Y[7] = ev ? sh[2][1] : u[3][1];
  const bool mid = (lg == 1) || (lg == 2);
#pragma unroll
  for (int j = 0; j < 8; j++) {
    const unsigned int z = (unsigned int)__shfl_xor((int)Y[j], 48, 64);
    Y[j] = mid ? z : Y[j];
  }
  union U8 { unsigned int u[4]; bf16x8 v; };
  U8 p0, p1;
  p0.u[0] = Y[0]; p0.u[1] = Y[1]; p0.u[2] = Y[4]; p0.u[3] = Y[5];
  p1.u[0] = Y[2]; p1.u[1] = Y[3]; p1.u[2] = Y[6]; p1.u[3] = Y[7];
  pbv0 = p0.v;
  pbv1 = p1.v;
}

// ---------------- fused flash attention (paired q-tiles, 8 waves) ----------
__global__ __launch_bounds__(512, 8) void attn_fused(const bf16_t* __restrict__ qp,
                                                     const bf16_t* __restrict__ kp,
                                                     const bf16_t* __restrict__ vt,
                                                     const int* __restrict__ pad,
                                                     bf16_t* __restrict__ outp) {
  __shared__ bf16_t Ks[2][64 * 64];   // [key][dh], XOR-swizzled
  __shared__ bf16_t Vts[2][64 * 64];  // [dh][key], XOR-swizzled
  __shared__ int padI[1024];
  __shared__ int sfl[8], sfh[8];
  const int t = threadIdx.x, w = t >> 6, l = t & 63, lr = l & 15, lg = l >> 4;
  const int L = (int)blockIdx.x;
  const int bh = (L & 7) + ((L >> 6) << 3);
  const int j = (L >> 3) & 7;
  const int b = bh >> 4, h = bh & 15;
  const int lo = j, hi = 15 - j;

  const int srow = t >> 3, sc = t & 7;
  const int gc = sc ^ (srow & 7);  // pre-swizzled global chunk
  const bf16_t* kgb = kp + (size_t)(b * 1024 + srow) * 1024 + h * 64 + gc * 8;
  const bf16_t* vgb = vt + (size_t)(bh * 64 + srow) * 1024 + gc * 8;

  auto stage = [&](int bufi, int k0s) {
    gl_lds16(kgb + (size_t)k0s * 1024, (char*)(Ks[bufi]) + t * 16);
    gl_lds16(vgb + k0s,                (char*)(Vts[bufi]) + t * 16);
  };

  // degenerate-row checks: any unpadded key in [0, lo*64] / [0, hi*64]?
  bool unl = false, unh = false;
  for (int jj = t; jj <= hi * 64; jj += 512) {
    const bool u = (pad[b * 1024 + jj] == 0);
    unh |= u;
    unl |= (u && (jj <= lo * 64));
  }
  const bool al = __any(unl), ah = __any(unh);
  if (l == 0) { sfl[w] = al ? 1 : 0; sfh[w] = ah ? 1 : 0; }

  stage(0, 0);
  if (t < 256) gl_lds16(pad + b * 1024 + t * 4, (char*)padI + t * 16);

  // this wave's q-tile: waves 0-3 -> hi, waves 4-7 -> lo
  const int mytile = (w < 4) ? hi : lo;
  const int qrow_l = mytile * 64 + (w & 3) * 16 + lr;  // lane's q row
  const int base16 = mytile * 64 + (w & 3) * 16;
  const bf16_t* qg = qp + (size_t)(b * 1024 + qrow_l) * 1024 + h * 64 + lg * 8;
  const bf16x8 qa0 = *reinterpret_cast<const bf16x8*>(qg);
  const bf16x8 qa1 = *reinterpret_cast<const bf16x8*>(qg + 32);

  __syncthreads();  // sf ready; drains tile-0 staging + padI
  int ul = 0, uh = 0;
#pragma unroll
  for (int i = 0; i < 8; i++) { ul |= sfl[i]; uh |= sfh[i]; }
  const bool mydeg = (w < 4) ? (uh == 0) : (ul == 0);
  const int ktEnd = (ul == 0) ? 16 : (hi + 1);

  f32x4 o[4] = {};
  float m_ = -INFINITY, ld_ = 0.0f;

  for (int kt = 0; kt < ktEnd; ++kt) {
    const int cur = kt & 1;
    if (kt + 1 < ktEnd) {
      stage(cur ^ 1, (kt + 1) * 64);
      asm volatile("s_waitcnt vmcnt(2)" ::: "memory");
    } else {
      asm volatile("s_waitcnt vmcnt(0)" ::: "memory");
    }
    __builtin_amdgcn_s_barrier();

    if (kt <= mytile || mydeg) {
      const char* Kb = (const char*)(Ks[cur]);
      const char* Vb = (const char*)(Vts[cur]);
      const int k0 = kt * 64;

      // S^T = K * Q^T : s[nt][i] = score[key=k0+nt*16+lg*4+i][q=qrow_l]
      f32x4 s[4] = {};
#pragma unroll
      for (int nt = 0; nt < 4; nt++) {
        const int row = nt * 16 + lr;
        const int sw = (row & 7) << 4;
        bf16x8 kb0 = *reinterpret_cast<const bf16x8*>(Kb + row * 128 + ((lg * 16) ^ sw));
        bf16x8 kb1 = *reinterpret_cast<const bf16x8*>(Kb + row * 128 + ((lg * 16 + 64) ^ sw));
        s[nt] = MFMA16(kb0, qa0, s[nt]);
        s[nt] = MFMA16(kb1, qa1, s[nt]);
      }

      // masking — reference f32 arithmetic exactly (qp pre-scaled by 1/8)
      const bool nc = (k0 + 63 > base16);
#pragma unroll
      for (int nt = 0; nt < 4; nt++) {
        const int kc4 = k0 + nt * 16 + lg * 4;
        const int4 pd = *reinterpret_cast<const int4*>(&padI[kc4]);
        const int pdv[4] = {pd.x, pd.y, pd.z, pd.w};
#pragma unroll
        for (int i = 0; i < 4; i++) {
          float v = s[nt][i];
          if (pdv[i]) v = NEGV;
          if (nc && (kc4 + i > qrow_l)) v += NEGV;
          s[nt][i] = v;
        }
      }

      // row max: 15 reg-local fmax + 2 shfl
      float mx = s[0][0];
#pragma unroll
      for (int nt = 0; nt < 4; nt++)
#pragma unroll
        for (int i = 0; i < 4; i++) mx = fmaxf(mx, s[nt][i]);
      mx = fmaxf(mx, __shfl_xor(mx, 16, 64));
      mx = fmaxf(mx, __shfl_xor(mx, 32, 64));

      if (!__all(mx <= m_ - 88.0f)) {          // dynamic underflow skip
        if (!__all(mx <= m_ + 8.0f)) {         // defer-max rescale
          const float mn = fmaxf(m_, mx);
          const float scl = __expf(m_ - mn);
          m_ = mn;
          ld_ *= scl;
#pragma unroll
          for (int nt = 0; nt < 4; nt++) o[nt] *= scl;
        }
        float a = 0.0f;
#pragma unroll
        for (int nt = 0; nt < 4; nt++)
#pragma unroll
          for (int i = 0; i < 4; i++) {
            const float p = __expf(s[nt][i] - m_);
            s[nt][i] = p;
            a += p;
          }
        a += __shfl_xor(a, 16, 64);
        a += __shfl_xor(a, 32, 64);
        ld_ += a;

        bf16x8 pb0, pb1;
        pack_bfly(s, lg, pb0, pb1);

        // PV: O^T[d][q] += V^T[d][k] * P^T[k][q]
#pragma unroll
        for (int nt = 0; nt < 4; nt++) {
          const int vrow = nt * 16 + lr;
          const int vsw = (vrow & 7) << 4;
          bf16x8 vf0 = *reinterpret_cast<const bf16x8*>(Vb + vrow * 128 + ((lg * 16) ^ vsw));
          bf16x8 vf1 = *reinterpret_cast<const bf16x8*>(Vb + vrow * 128 + ((64 + lg * 16) ^ vsw));
          o[nt] = MFMA16(vf0, pb0, o[nt]);
          o[nt] = MFMA16(vf1, pb1, o[nt]);
        }
      }
    }
    __builtin_amdgcn_s_barrier();  // protect buf[cur] before next prefetch
  }

  // epilogue: o^T[d = nt*16+lg*4+i][q = lr], normalize, 8B vector stores
  const float rinv = 1.0f / ld_;
#pragma unroll
  for (int nt = 0; nt < 4; nt++) {
    bf16x4 r = {(bf16_t)(o[nt][0] * rinv), (bf16_t)(o[nt][1] * rinv),
                (bf16_t)(o[nt][2] * rinv), (bf16_t)(o[nt][3] * rinv)};
    *reinterpret_cast<bf16x4*>(outp + (size_t)(b * 1024 + qrow_l) * 1024 + h * 64 + nt * 16 + lg * 4) = r;
  }
}

// ---------------------------------------------------------------------------
extern "C" void kernel_launch(void* const* d_in, const int* in_sizes, int n_in,
                              void* d_out, int out_size, void* d_ws, size_t ws_size,
                              hipStream_t stream) {
  const float* q   = (const float*)d_in[0];
  const float* k   = (const float*)d_in[1];
  const float* v   = (const float*)d_in[2];
  const int*   pad = (const int*)d_in[3];
  const float* wq  = (const float*)d_in[5];
  const float* bq  = (const float*)d_in[6];
  const float* wk  = (const float*)d_in[7];
  const float* wv  = (const float*)d_in[8];
  const float* bv  = (const float*)d_in[9];
  const float* wo  = (const float*)d_in[10];
  const float* bo  = (const float*)d_in[11];

  char* ws = (char*)d_ws;
  const size_t MiB = 1024 * 1024;
  bf16_t* qbf = (bf16_t*)(ws + 0 * MiB);
  bf16_t* kbf = (bf16_t*)(ws + 16 * MiB);
  bf16_t* vbf = (bf16_t*)(ws + 32 * MiB);
  bf16_t* qp  = (bf16_t*)(ws + 48 * MiB);
  bf16_t* kp  = (bf16_t*)(ws + 64 * MiB);
  bf16_t* vtw = (bf16_t*)(ws + 80 * MiB);
  bf16_t* wqb = (bf16_t*)(ws + 96 * MiB);
  bf16_t* wkb = (bf16_t*)(ws + 98 * MiB);
  bf16_t* wvb = (bf16_t*)(ws + 100 * MiB);
  bf16_t* wob = (bf16_t*)(ws + 102 * MiB);
  bf16_t* attnO = qbf;  // qbf dead after q-projection

  cvt_all<<<14336, 256, 0, stream>>>(q, k, v, wq, wk, wv, wo,
                                     qbf, kbf, vbf, wqb, wkb, wvb, wob);

  gemm_qkv<<<dim3(512, 3), 256, 0, stream>>>(qbf, kbf, vbf, wqb, wkb, wvb, bq, bv, qp, kp, vtw);

  attn_fused<<<1024, 512, 0, stream>>>(qp, kp, vtw, pad, attnO);

  gemm_out<<<512, 256, 0, stream>>>(attnO, wob, bo, (float*)d_out);
}